// Round 1
// baseline (318.315 us; speedup 1.0000x reference)
//
#include <hip/hip_runtime.h>
#include <stdint.h>

typedef unsigned short u16;
typedef __attribute__((ext_vector_type(4))) float floatx4;
typedef __attribute__((ext_vector_type(8))) __bf16 bf16x8;

__device__ __forceinline__ u16 f2bf(float f) {
  uint32_t u = __float_as_uint(f);
  u += 0x7FFFu + ((u >> 16) & 1u);
  return (u16)(u >> 16);
}

// ---------------- cast x: f32 -> bf16, 8 elems/thread ----------------
__global__ __launch_bounds__(256) void cast_x_kernel(const float* __restrict__ x,
                                                     u16* __restrict__ out) {
  int i = blockIdx.x * 256 + threadIdx.x;
  const float4* p = (const float4*)x;
  float4 a = p[(size_t)i * 2];
  float4 b = p[(size_t)i * 2 + 1];
  uint32_t w0 = (uint32_t)f2bf(a.x) | ((uint32_t)f2bf(a.y) << 16);
  uint32_t w1 = (uint32_t)f2bf(a.z) | ((uint32_t)f2bf(a.w) << 16);
  uint32_t w2 = (uint32_t)f2bf(b.x) | ((uint32_t)f2bf(b.y) << 16);
  uint32_t w3 = (uint32_t)f2bf(b.z) | ((uint32_t)f2bf(b.w) << 16);
  *(uint4*)(out + (size_t)i * 8) = make_uint4(w0, w1, w2, w3);
}

// ---------------- pack W^T (bf16) for QKV + packed bias ----------------
__global__ __launch_bounds__(256) void prep_wqkv_kernel(
    const float* __restrict__ Wq, const float* __restrict__ Wk, const float* __restrict__ Wv,
    const float* __restrict__ bq, const float* __restrict__ bk, const float* __restrict__ bv,
    u16* __restrict__ Wt, float* __restrict__ bias) {
  int id = blockIdx.x * 256 + threadIdx.x;   // over 2304*768
  int n = id / 768, k = id - n * 768;
  const float* W; const float* bs; int nn;
  if (n < 768)       { W = Wq; bs = bq; nn = n; }
  else if (n < 1536) { W = Wk; bs = bk; nn = n - 768; }
  else               { W = Wv; bs = bv; nn = n - 1536; }
  Wt[id] = f2bf(W[(size_t)k * 768 + nn]);   // Wt[n][k] = W[k][n]
  if (k == 0) bias[n] = bs[nn];
}

__global__ __launch_bounds__(256) void prep_wo_kernel(const float* __restrict__ Wo,
                                                      u16* __restrict__ Wt) {
  int id = blockIdx.x * 256 + threadIdx.x;   // over 768*768
  int n = id / 768, k = id - n * 768;
  Wt[id] = f2bf(Wo[(size_t)k * 768 + n]);
}

// ---------------- GEMM: C[m,n] = sum_k A[m,k]*Bt[n,k] + bias[n] ----------------
// A [M,768] bf16, Bt [N,768] bf16. 128x128 tile, BK=32, 4 waves (2x2), m97 structure.
__device__ __forceinline__ void gload16(const void* g, void* l) {
  __builtin_amdgcn_global_load_lds((const __attribute__((address_space(1))) void*)g,
                                   (__attribute__((address_space(3))) void*)l,
                                   16, 0, 0);
}

template <int OUTF32>
__global__ __launch_bounds__(256) void gemm_bt_kernel(
    const u16* __restrict__ A, const u16* __restrict__ Bt,
    const float* __restrict__ bias, void* __restrict__ Cv, int ldc) {
  __shared__ __align__(16) u16 Alds[128 * 32];
  __shared__ __align__(16) u16 Blds[128 * 32];
  const int m0 = blockIdx.x * 128, n0 = blockIdx.y * 128;
  const int tid = threadIdx.x;
  const int lane = tid & 63, wid = tid >> 6;
  const int wr = wid >> 1, wc = wid & 1;
  const int l15 = lane & 15, l4 = lane >> 4;

  floatx4 zz = {0.f, 0.f, 0.f, 0.f};
  floatx4 acc[4][4];
#pragma unroll
  for (int i = 0; i < 4; ++i)
#pragma unroll
    for (int j = 0; j < 4; ++j) acc[i][j] = zz;

  for (int kt = 0; kt < 768; kt += 32) {
#pragma unroll
    for (int c = 0; c < 2; ++c) {
      int idx = (wid * 2 + c) * 64 + lane;    // 16B-chunk id, 0..511
      int row = idx >> 2, kc = idx & 3;
      gload16(A + (size_t)(m0 + row) * 768 + kt + kc * 8,
              (char*)Alds + (wid * 2 + c) * 1024);
      gload16(Bt + (size_t)(n0 + row) * 768 + kt + kc * 8,
              (char*)Blds + (wid * 2 + c) * 1024);
    }
    __syncthreads();
    bf16x8 af[4], bfr[4];
#pragma unroll
    for (int i = 0; i < 4; ++i) {
      af[i]  = *(const bf16x8*)&Alds[(wr * 64 + i * 16 + l15) * 32 + l4 * 8];
      bfr[i] = *(const bf16x8*)&Blds[(wc * 64 + i * 16 + l15) * 32 + l4 * 8];
    }
#pragma unroll
    for (int i = 0; i < 4; ++i)
#pragma unroll
      for (int j = 0; j < 4; ++j)
        acc[i][j] = __builtin_amdgcn_mfma_f32_16x16x32_bf16(af[i], bfr[j], acc[i][j], 0, 0, 0);
    __syncthreads();
  }

#pragma unroll
  for (int i = 0; i < 4; ++i) {
    int row = m0 + wr * 64 + i * 16 + l4 * 4;
#pragma unroll
    for (int j = 0; j < 4; ++j) {
      int col = n0 + wc * 64 + j * 16 + l15;
      float bv = bias[col];
#pragma unroll
      for (int r = 0; r < 4; ++r) {
        float v = acc[i][j][r] + bv;
        if (OUTF32) ((float*)Cv)[(size_t)(row + r) * ldc + col] = v;
        else        ((u16*)Cv)[(size_t)(row + r) * ldc + col] = f2bf(v);
      }
    }
  }
}

// ---------------- fused attention ----------------
// grid (8 qtiles, 12 heads, 32 batch), 256 thr (4 waves), each wave = 16 q-rows.
__global__ __launch_bounds__(256) void attn_kernel(const u16* __restrict__ qkv,
                                                   const float* __restrict__ mask,
                                                   u16* __restrict__ ctx) {
  __shared__ __align__(16) char smem_v[32768];  // V^T half: [64 d][256 s] bf16, swizzled
  __shared__ __align__(16) char smem_p[8192];   // per-wave P chunk [16][64] bf16, swizzled
  const int qt = blockIdx.x, h = blockIdx.y, b = blockIdx.z;
  const int tid = threadIdx.x;
  const int lane = tid & 63, w = tid >> 6;
  const int l15 = lane & 15, l4 = lane >> 4;

  const u16* base = qkv + (size_t)b * 512 * 2304 + h * 64;
  const u16* Qg = base;
  const u16* Kg = base + 768;
  const u16* Vg = base + 1536;

  auto stageV = [&](int hs) {  // stage s in [hs*256, hs*256+256) transposed into smem_v
#pragma unroll
    for (int it = 0; it < 4; ++it) {
      int task = it * 256 + tid;         // 0..1023
      int doct = task & 7, sp = task >> 3;
      int sl = sp * 2, d0 = doct * 8;
      const u16* vp = Vg + (size_t)(hs * 256 + sl) * 2304 + d0;
      uint4 va = *(const uint4*)vp;
      uint4 vb = *(const uint4*)(vp + 2304);
      const u16* pa = (const u16*)&va;
      const u16* pb = (const u16*)&vb;
#pragma unroll
      for (int j = 0; j < 8; ++j) {
        int d = d0 + j;
        uint32_t val = (uint32_t)pa[j] | ((uint32_t)pb[j] << 16);
        *(uint32_t*)(smem_v + d * 512 + ((2 * sl) ^ ((d & 7) << 4))) = val;
      }
    }
  };

  stageV(0);  // issue first so V global loads overlap QK^T

  // ---- QK^T: K operands straight from global (L2-resident) ----
  const int qrow = qt * 64 + w * 16 + l15;
  const u16* qp = Qg + (size_t)qrow * 2304 + l4 * 8;
  bf16x8 qf0 = *(const bf16x8*)qp;
  bf16x8 qf1 = *(const bf16x8*)(qp + 32);

  floatx4 zz = {0.f, 0.f, 0.f, 0.f};
  floatx4 sacc[32];
#pragma unroll
  for (int ct = 0; ct < 32; ++ct) sacc[ct] = zz;
#pragma unroll
  for (int ct = 0; ct < 32; ++ct) {
    const u16* kp = Kg + (size_t)(ct * 16 + l15) * 2304 + l4 * 8;
    bf16x8 k0 = *(const bf16x8*)kp;
    bf16x8 k1 = *(const bf16x8*)(kp + 32);
    sacc[ct] = __builtin_amdgcn_mfma_f32_16x16x32_bf16(qf0, k0, sacc[ct], 0, 0, 0);
    sacc[ct] = __builtin_amdgcn_mfma_f32_16x16x32_bf16(qf1, k1, sacc[ct], 0, 0, 0);
  }

  // ---- softmax (full row in registers; reduce over 16-lane group) ----
  const float* mrow = mask + (size_t)b * 512;
  float mx[4] = {-1e30f, -1e30f, -1e30f, -1e30f};
#pragma unroll
  for (int ct = 0; ct < 32; ++ct) {
    float mv = mrow[ct * 16 + l15];
#pragma unroll
    for (int j = 0; j < 4; ++j) {
      float v = sacc[ct][j] * 0.125f + mv;
      sacc[ct][j] = v;
      mx[j] = fmaxf(mx[j], v);
    }
  }
#pragma unroll
  for (int xm = 1; xm < 16; xm <<= 1)
#pragma unroll
    for (int j = 0; j < 4; ++j) mx[j] = fmaxf(mx[j], __shfl_xor(mx[j], xm, 64));
  float sum[4] = {0.f, 0.f, 0.f, 0.f};
#pragma unroll
  for (int ct = 0; ct < 32; ++ct)
#pragma unroll
    for (int j = 0; j < 4; ++j) {
      float e = __expf(sacc[ct][j] - mx[j]);
      sacc[ct][j] = e;
      sum[j] += e;
    }
#pragma unroll
  for (int xm = 1; xm < 16; xm <<= 1)
#pragma unroll
    for (int j = 0; j < 4; ++j) sum[j] += __shfl_xor(sum[j], xm, 64);
  float rinv[4];
#pragma unroll
  for (int j = 0; j < 4; ++j) rinv[j] = 1.0f / sum[j];
#pragma unroll
  for (int ct = 0; ct < 32; ++ct)
#pragma unroll
    for (int j = 0; j < 4; ++j) sacc[ct][j] *= rinv[j];

  __syncthreads();  // V half0 staged by all threads

  floatx4 oacc[4];
#pragma unroll
  for (int dt = 0; dt < 4; ++dt) oacc[dt] = zz;

  char* pw = smem_p + w * 2048;
  auto pv = [&](int kc) {  // kc in 0..7, 64 s-cols per chunk
#pragma unroll
    for (int cc = 0; cc < 4; ++cc) {
      int c = cc * 16 + l15;
      int ct = kc * 4 + cc;
#pragma unroll
      for (int j = 0; j < 4; ++j) {
        int r = l4 * 4 + j;
        *(u16*)(pw + r * 128 + ((2 * c) ^ ((r & 7) << 4))) = f2bf(sacc[ct][j]);
      }
    }
#pragma unroll
    for (int ks = 0; ks < 2; ++ks) {
      int c0 = ks * 32 + l4 * 8;
      bf16x8 pf = *(const bf16x8*)(pw + l15 * 128 + ((2 * c0) ^ ((l15 & 7) << 4)));
      int sl = (kc & 3) * 64 + c0;   // s-local within the 256-wide half
#pragma unroll
      for (int dt = 0; dt < 4; ++dt) {
        int dd = dt * 16 + l15;
        bf16x8 vf = *(const bf16x8*)(smem_v + dd * 512 + ((2 * sl) ^ ((dd & 7) << 4)));
        oacc[dt] = __builtin_amdgcn_mfma_f32_16x16x32_bf16(pf, vf, oacc[dt], 0, 0, 0);
      }
    }
  };

#pragma unroll
  for (int kc = 0; kc < 4; ++kc) pv(kc);
  __syncthreads();       // all waves done reading V half0
  stageV(1);
  __syncthreads();       // V half1 staged
#pragma unroll
  for (int kc = 4; kc < 8; ++kc) pv(kc);

  const size_t obase = ((size_t)b * 512 + qt * 64 + w * 16) * 768 + h * 64;
#pragma unroll
  for (int dt = 0; dt < 4; ++dt)
#pragma unroll
    for (int r = 0; r < 4; ++r)
      ctx[obase + (size_t)(l4 * 4 + r) * 768 + dt * 16 + l15] = f2bf(oacc[dt][r]);
}

// ---------------- launch ----------------
extern "C" void kernel_launch(void* const* d_in, const int* in_sizes, int n_in,
                              void* d_out, int out_size, void* d_ws, size_t ws_size,
                              hipStream_t stream) {
  const float* x    = (const float*)d_in[0];
  const float* mask = (const float*)d_in[1];
  const float* Wq   = (const float*)d_in[2];
  const float* bq   = (const float*)d_in[3];
  const float* Wk   = (const float*)d_in[4];
  const float* bk   = (const float*)d_in[5];
  const float* Wv   = (const float*)d_in[6];
  const float* bv   = (const float*)d_in[7];
  const float* Wo   = (const float*)d_in[8];
  const float* bo   = (const float*)d_in[9];
  float* out = (float*)d_out;

  char* ws = (char*)d_ws;
  u16*   xb   = (u16*)ws;                          // 16384*768   bf16 = 25,165,824 B
  u16*   ctx  = (u16*)(ws + 25165824);             // 16384*768   bf16
  u16*   qkv  = (u16*)(ws + 50331648);             // 16384*2304  bf16 = 75,497,472 B
  u16*   wtq  = (u16*)(ws + 125829120);            // 2304*768    bf16
  u16*   wto  = (u16*)(ws + 129368064);            // 768*768     bf16
  float* bqkv = (float*)(ws + 130547712);          // 2304        f32

  cast_x_kernel<<<6144, 256, 0, stream>>>(x, xb);
  prep_wqkv_kernel<<<6912, 256, 0, stream>>>(Wq, Wk, Wv, bq, bk, bv, wtq, bqkv);
  prep_wo_kernel<<<2304, 256, 0, stream>>>(Wo, wto);
  gemm_bt_kernel<0><<<dim3(128, 18), 256, 0, stream>>>(xb, wtq, bqkv, (void*)qkv, 2304);
  attn_kernel<<<dim3(8, 12, 32), 256, 0, stream>>>(qkv, mask, ctx);
  gemm_bt_kernel<1><<<dim3(128, 6), 256, 0, stream>>>(ctx, wto, bo, (void*)out, 768);
}

// Round 2
// 228.506 us; speedup vs baseline: 1.3930x; 1.3930x over previous
//
#include <hip/hip_runtime.h>
#include <stdint.h>

typedef unsigned short u16;
typedef __attribute__((ext_vector_type(4))) float floatx4;
typedef __attribute__((ext_vector_type(8))) __bf16 bf16x8;

__device__ __forceinline__ u16 f2bf(float f) {
  uint32_t u = __float_as_uint(f);
  u += 0x7FFFu + ((u >> 16) & 1u);
  return (u16)(u >> 16);
}

// ---------------- cast x: f32 -> bf16, 8 elems/thread ----------------
__global__ __launch_bounds__(256) void cast_x_kernel(const float* __restrict__ x,
                                                     u16* __restrict__ out) {
  int i = blockIdx.x * 256 + threadIdx.x;
  const float4* p = (const float4*)x;
  float4 a = p[(size_t)i * 2];
  float4 b = p[(size_t)i * 2 + 1];
  uint32_t w0 = (uint32_t)f2bf(a.x) | ((uint32_t)f2bf(a.y) << 16);
  uint32_t w1 = (uint32_t)f2bf(a.z) | ((uint32_t)f2bf(a.w) << 16);
  uint32_t w2 = (uint32_t)f2bf(b.x) | ((uint32_t)f2bf(b.y) << 16);
  uint32_t w3 = (uint32_t)f2bf(b.z) | ((uint32_t)f2bf(b.w) << 16);
  *(uint4*)(out + (size_t)i * 8) = make_uint4(w0, w1, w2, w3);
}

// ---------------- pack W^T (bf16) for QKV + packed bias ----------------
__global__ __launch_bounds__(256) void prep_wqkv_kernel(
    const float* __restrict__ Wq, const float* __restrict__ Wk, const float* __restrict__ Wv,
    const float* __restrict__ bq, const float* __restrict__ bk, const float* __restrict__ bv,
    u16* __restrict__ Wt, float* __restrict__ bias) {
  int id = blockIdx.x * 256 + threadIdx.x;   // over 2304*768
  int n = id / 768, k = id - n * 768;
  const float* W; const float* bs; int nn;
  if (n < 768)       { W = Wq; bs = bq; nn = n; }
  else if (n < 1536) { W = Wk; bs = bk; nn = n - 768; }
  else               { W = Wv; bs = bv; nn = n - 1536; }
  Wt[id] = f2bf(W[(size_t)k * 768 + nn]);   // Wt[n][k] = W[k][n]
  if (k == 0) bias[n] = bs[nn];
}

__global__ __launch_bounds__(256) void prep_wo_kernel(const float* __restrict__ Wo,
                                                      u16* __restrict__ Wt) {
  int id = blockIdx.x * 256 + threadIdx.x;   // over 768*768
  int n = id / 768, k = id - n * 768;
  Wt[id] = f2bf(Wo[(size_t)k * 768 + n]);
}

// ---------------- GEMM: C[m,n] = sum_k A[m,k]*Bt[n,k] + bias[n] ----------------
__device__ __forceinline__ void gload16(const void* g, void* l) {
  __builtin_amdgcn_global_load_lds((const __attribute__((address_space(1))) void*)g,
                                   (__attribute__((address_space(3))) void*)l,
                                   16, 0, 0);
}

template <int OUTF32>
__global__ __launch_bounds__(256) void gemm_bt_kernel(
    const u16* __restrict__ A, const u16* __restrict__ Bt,
    const float* __restrict__ bias, void* __restrict__ Cv, int ldc) {
  __shared__ __align__(16) u16 Alds[128 * 32];
  __shared__ __align__(16) u16 Blds[128 * 32];
  const int m0 = blockIdx.x * 128, n0 = blockIdx.y * 128;
  const int tid = threadIdx.x;
  const int lane = tid & 63, wid = tid >> 6;
  const int wr = wid >> 1, wc = wid & 1;
  const int l15 = lane & 15, l4 = lane >> 4;

  floatx4 zz = {0.f, 0.f, 0.f, 0.f};
  floatx4 acc[4][4];
#pragma unroll
  for (int i = 0; i < 4; ++i)
#pragma unroll
    for (int j = 0; j < 4; ++j) acc[i][j] = zz;

  for (int kt = 0; kt < 768; kt += 32) {
#pragma unroll
    for (int c = 0; c < 2; ++c) {
      int idx = (wid * 2 + c) * 64 + lane;    // 16B-chunk id, 0..511
      int row = idx >> 2, kc = idx & 3;
      gload16(A + (size_t)(m0 + row) * 768 + kt + kc * 8,
              (char*)Alds + (wid * 2 + c) * 1024);
      gload16(Bt + (size_t)(n0 + row) * 768 + kt + kc * 8,
              (char*)Blds + (wid * 2 + c) * 1024);
    }
    __syncthreads();
    bf16x8 af[4], bfr[4];
#pragma unroll
    for (int i = 0; i < 4; ++i) {
      af[i]  = *(const bf16x8*)&Alds[(wr * 64 + i * 16 + l15) * 32 + l4 * 8];
      bfr[i] = *(const bf16x8*)&Blds[(wc * 64 + i * 16 + l15) * 32 + l4 * 8];
    }
#pragma unroll
    for (int i = 0; i < 4; ++i)
#pragma unroll
      for (int j = 0; j < 4; ++j)
        acc[i][j] = __builtin_amdgcn_mfma_f32_16x16x32_bf16(af[i], bfr[j], acc[i][j], 0, 0, 0);
    __syncthreads();
  }

#pragma unroll
  for (int i = 0; i < 4; ++i) {
    int row = m0 + wr * 64 + i * 16 + l4 * 4;
#pragma unroll
    for (int j = 0; j < 4; ++j) {
      int col = n0 + wc * 64 + j * 16 + l15;
      float bv = bias[col];
#pragma unroll
      for (int r = 0; r < 4; ++r) {
        float v = acc[i][j][r] + bv;
        if (OUTF32) ((float*)Cv)[(size_t)(row + r) * ldc + col] = v;
        else        ((u16*)Cv)[(size_t)(row + r) * ldc + col] = f2bf(v);
      }
    }
  }
}

// ---------------- fused attention ----------------
// 768 blocks (2 q-halves x 12 heads x 32 batch), 512 thr (8 waves), wave = 32 q-rows.
// K[512][64] and V^T[64][512] staged ONCE per block in swizzled LDS.
__global__ __launch_bounds__(512) void attn_kernel(const u16* __restrict__ qkv,
                                                   const float* __restrict__ mask,
                                                   u16* __restrict__ ctx) {
  __shared__ __align__(16) char sK[65536];   // [512][64] bf16, byte ^= ((s&7)<<4)
  __shared__ __align__(16) char sV[65536];   // [64][512] bf16 (V^T), byte ^= ((d&7)<<4)
  __shared__ __align__(16) char sP[16384];   // 8 waves x [16][64] bf16, byte ^= ((r&7)<<4)

  // XCD-aware bijective swizzle: 768 = 8 * 96; q-half partners share an XCD.
  const int bid = blockIdx.x;
  const int wg = (bid & 7) * 96 + (bid >> 3);
  const int qh = wg & 1;
  const int h = (wg >> 1) % 12;
  const int b = wg / 24;

  const int tid = threadIdx.x;
  const int lane = tid & 63, w = tid >> 6;
  const int l15 = lane & 15, l4 = lane >> 4;

  const u16* base = qkv + (size_t)b * 512 * 2304 + h * 64;
  const u16* Qg = base;
  const u16* Kg = base + 768;
  const u16* Vg = base + 1536;

  // ---- stage K via global_load_lds: linear LDS dest + inverse-swizzled source ----
  {
    int rl = lane >> 3, c16 = lane & 7;
    int csw = c16 ^ rl;   // row&7 == lane>>3 since row-blocks are 8-aligned
#pragma unroll
    for (int it = 0; it < 8; ++it) {
      int row = (it * 8 + w) * 8 + rl;
      gload16(Kg + (size_t)row * 2304 + csw * 8, (char*)sK + (it * 8 + w) * 1024);
    }
  }
  // ---- stage V transposed (reg-staged) ----
#pragma unroll
  for (int it = 0; it < 4; ++it) {
    int doct = lane & 7;                       // task&7
    int sp = it * 64 + w * 8 + (lane >> 3);    // 0..255 (s pairs)
    int sl = sp * 2, d0 = doct * 8;
    const u16* vp = Vg + (size_t)sl * 2304 + d0;
    uint4 va = *(const uint4*)vp;
    uint4 vb = *(const uint4*)(vp + 2304);
    const u16* pa = (const u16*)&va;
    const u16* pb = (const u16*)&vb;
#pragma unroll
    for (int j = 0; j < 8; ++j) {
      int d = d0 + j;
      uint32_t val = (uint32_t)pa[j] | ((uint32_t)pb[j] << 16);
      *(uint32_t*)(sV + d * 1024 + ((2 * sl) ^ ((d & 7) << 4))) = val;
    }
  }
  __syncthreads();   // K (vmcnt) + V (lgkm) staged

  char* pw = sP + w * 2048;
  floatx4 zz = {0.f, 0.f, 0.f, 0.f};
  const float* mrow = mask + (size_t)b * 512;

  for (int t = 0; t < 2; ++t) {
    const int qb = qh * 256 + (w * 2 + t) * 16;
    const u16* qp = Qg + (size_t)(qb + l15) * 2304 + l4 * 8;
    bf16x8 qf0 = *(const bf16x8*)qp;
    bf16x8 qf1 = *(const bf16x8*)(qp + 32);

    floatx4 sacc[32];
#pragma unroll
    for (int ct = 0; ct < 32; ++ct) sacc[ct] = zz;
#pragma unroll
    for (int ct = 0; ct < 32; ++ct) {
      int s = ct * 16 + l15;
      const char* kr = sK + s * 128;
      int swz = (s & 7) << 4;
      bf16x8 k0 = *(const bf16x8*)(kr + ((l4 * 16) ^ swz));
      bf16x8 k1 = *(const bf16x8*)(kr + ((64 + l4 * 16) ^ swz));
      sacc[ct] = __builtin_amdgcn_mfma_f32_16x16x32_bf16(qf0, k0, sacc[ct], 0, 0, 0);
      sacc[ct] = __builtin_amdgcn_mfma_f32_16x16x32_bf16(qf1, k1, sacc[ct], 0, 0, 0);
    }

    // ---- softmax: full row in regs, reduce over 16-lane group ----
    float mx[4] = {-1e30f, -1e30f, -1e30f, -1e30f};
#pragma unroll
    for (int ct = 0; ct < 32; ++ct) {
      float mv = mrow[ct * 16 + l15];
#pragma unroll
      for (int j = 0; j < 4; ++j) {
        float v = sacc[ct][j] * 0.125f + mv;
        sacc[ct][j] = v;
        mx[j] = fmaxf(mx[j], v);
      }
    }
#pragma unroll
    for (int xm = 1; xm < 16; xm <<= 1)
#pragma unroll
      for (int j = 0; j < 4; ++j) mx[j] = fmaxf(mx[j], __shfl_xor(mx[j], xm, 64));
    float sum[4] = {0.f, 0.f, 0.f, 0.f};
#pragma unroll
    for (int ct = 0; ct < 32; ++ct)
#pragma unroll
      for (int j = 0; j < 4; ++j) {
        float e = __expf(sacc[ct][j] - mx[j]);
        sacc[ct][j] = e;
        sum[j] += e;
      }
#pragma unroll
    for (int xm = 1; xm < 16; xm <<= 1)
#pragma unroll
      for (int j = 0; j < 4; ++j) sum[j] += __shfl_xor(sum[j], xm, 64);
    float rinv[4];
#pragma unroll
    for (int j = 0; j < 4; ++j) rinv[j] = 1.0f / sum[j];
#pragma unroll
    for (int ct = 0; ct < 32; ++ct)
#pragma unroll
      for (int j = 0; j < 4; ++j) sacc[ct][j] *= rinv[j];

    // ---- PV: per-wave P chunk through LDS, V^T from LDS ----
    floatx4 oacc[4];
#pragma unroll
    for (int dt = 0; dt < 4; ++dt) oacc[dt] = zz;
#pragma unroll
    for (int kc = 0; kc < 8; ++kc) {
#pragma unroll
      for (int cc = 0; cc < 4; ++cc) {
        int ct = kc * 4 + cc;
#pragma unroll
        for (int j = 0; j < 4; ++j) {
          int r = l4 * 4 + j;
          *(u16*)(pw + r * 128 + ((2 * (cc * 16 + l15)) ^ ((r & 7) << 4))) = f2bf(sacc[ct][j]);
        }
      }
#pragma unroll
      for (int ks = 0; ks < 2; ++ks) {
        int c0 = ks * 32 + l4 * 8;
        bf16x8 pf = *(const bf16x8*)(pw + l15 * 128 + ((2 * c0) ^ ((l15 & 7) << 4)));
        int s0 = kc * 64 + c0;
#pragma unroll
        for (int dt = 0; dt < 4; ++dt) {
          int dd = dt * 16 + l15;
          bf16x8 vf = *(const bf16x8*)(sV + dd * 1024 + ((2 * s0) ^ ((dd & 7) << 4)));
          oacc[dt] = __builtin_amdgcn_mfma_f32_16x16x32_bf16(pf, vf, oacc[dt], 0, 0, 0);
        }
      }
    }

    const size_t obase = ((size_t)b * 512 + qb) * 768 + h * 64;
#pragma unroll
    for (int dt = 0; dt < 4; ++dt)
#pragma unroll
      for (int r = 0; r < 4; ++r)
        ctx[obase + (size_t)(l4 * 4 + r) * 768 + dt * 16 + l15] = f2bf(oacc[dt][r]);
  }
}

// ---------------- launch ----------------
extern "C" void kernel_launch(void* const* d_in, const int* in_sizes, int n_in,
                              void* d_out, int out_size, void* d_ws, size_t ws_size,
                              hipStream_t stream) {
  const float* x    = (const float*)d_in[0];
  const float* mask = (const float*)d_in[1];
  const float* Wq   = (const float*)d_in[2];
  const float* bq   = (const float*)d_in[3];
  const float* Wk   = (const float*)d_in[4];
  const float* bk   = (const float*)d_in[5];
  const float* Wv   = (const float*)d_in[6];
  const float* bv   = (const float*)d_in[7];
  const float* Wo   = (const float*)d_in[8];
  const float* bo   = (const float*)d_in[9];
  float* out = (float*)d_out;

  char* ws = (char*)d_ws;
  u16*   xb   = (u16*)ws;                          // 16384*768   bf16
  u16*   ctx  = (u16*)(ws + 25165824);             // 16384*768   bf16
  u16*   qkv  = (u16*)(ws + 50331648);             // 16384*2304  bf16
  u16*   wtq  = (u16*)(ws + 125829120);            // 2304*768    bf16
  u16*   wto  = (u16*)(ws + 129368064);            // 768*768     bf16
  float* bqkv = (float*)(ws + 130547712);          // 2304        f32

  cast_x_kernel<<<6144, 256, 0, stream>>>(x, xb);
  prep_wqkv_kernel<<<6912, 256, 0, stream>>>(Wq, Wk, Wv, bq, bk, bv, wtq, bqkv);
  prep_wo_kernel<<<2304, 256, 0, stream>>>(Wo, wto);
  gemm_bt_kernel<0><<<dim3(128, 18), 256, 0, stream>>>(xb, wtq, bqkv, (void*)qkv, 2304);
  attn_kernel<<<dim3(768), dim3(512), 0, stream>>>(qkv, mask, ctx);
  gemm_bt_kernel<1><<<dim3(128, 6), 256, 0, stream>>>(ctx, wto, bo, (void*)out, 768);
}

// Round 3
// 209.648 us; speedup vs baseline: 1.5183x; 1.0899x over previous
//
#include <hip/hip_runtime.h>
#include <stdint.h>

typedef unsigned short u16;
typedef __attribute__((ext_vector_type(4))) float floatx4;
typedef __attribute__((ext_vector_type(8))) __bf16 bf16x8;

__device__ __forceinline__ u16 f2bf(float f) {
  uint32_t u = __float_as_uint(f);
  u += 0x7FFFu + ((u >> 16) & 1u);
  return (u16)(u >> 16);
}

// ---------------- cast x: f32 -> bf16, 8 elems/thread ----------------
__global__ __launch_bounds__(256) void cast_x_kernel(const float* __restrict__ x,
                                                     u16* __restrict__ out) {
  int i = blockIdx.x * 256 + threadIdx.x;
  const float4* p = (const float4*)x;
  float4 a = p[(size_t)i * 2];
  float4 b = p[(size_t)i * 2 + 1];
  uint32_t w0 = (uint32_t)f2bf(a.x) | ((uint32_t)f2bf(a.y) << 16);
  uint32_t w1 = (uint32_t)f2bf(a.z) | ((uint32_t)f2bf(a.w) << 16);
  uint32_t w2 = (uint32_t)f2bf(b.x) | ((uint32_t)f2bf(b.y) << 16);
  uint32_t w3 = (uint32_t)f2bf(b.z) | ((uint32_t)f2bf(b.w) << 16);
  *(uint4*)(out + (size_t)i * 8) = make_uint4(w0, w1, w2, w3);
}

// ---------------- pack W^T (bf16) for QKV + packed bias ----------------
__global__ __launch_bounds__(256) void prep_wqkv_kernel(
    const float* __restrict__ Wq, const float* __restrict__ Wk, const float* __restrict__ Wv,
    const float* __restrict__ bq, const float* __restrict__ bk, const float* __restrict__ bv,
    u16* __restrict__ Wt, float* __restrict__ bias) {
  int id = blockIdx.x * 256 + threadIdx.x;   // over 2304*768
  int n = id / 768, k = id - n * 768;
  const float* W; const float* bs; int nn;
  if (n < 768)       { W = Wq; bs = bq; nn = n; }
  else if (n < 1536) { W = Wk; bs = bk; nn = n - 768; }
  else               { W = Wv; bs = bv; nn = n - 1536; }
  Wt[id] = f2bf(W[(size_t)k * 768 + nn]);   // Wt[n][k] = W[k][n]
  if (k == 0) bias[n] = bs[nn];
}

__global__ __launch_bounds__(256) void prep_wo_kernel(const float* __restrict__ Wo,
                                                      u16* __restrict__ Wt) {
  int id = blockIdx.x * 256 + threadIdx.x;   // over 768*768
  int n = id / 768, k = id - n * 768;
  Wt[id] = f2bf(Wo[(size_t)k * 768 + n]);
}

// ---------------- GEMM: C[m,n] = sum_k A[m,k]*Bt[n,k] + bias[n] ----------------
__device__ __forceinline__ void gload16(const void* g, void* l) {
  __builtin_amdgcn_global_load_lds((const __attribute__((address_space(1))) void*)g,
                                   (__attribute__((address_space(3))) void*)l,
                                   16, 0, 0);
}

template <int OUTF32>
__global__ __launch_bounds__(256) void gemm_bt_kernel(
    const u16* __restrict__ A, const u16* __restrict__ Bt,
    const float* __restrict__ bias, void* __restrict__ Cv, int ldc) {
  __shared__ __align__(16) u16 Alds[128 * 32];
  __shared__ __align__(16) u16 Blds[128 * 32];
  const int m0 = blockIdx.x * 128, n0 = blockIdx.y * 128;
  const int tid = threadIdx.x;
  const int lane = tid & 63, wid = tid >> 6;
  const int wr = wid >> 1, wc = wid & 1;
  const int l15 = lane & 15, l4 = lane >> 4;

  floatx4 zz = {0.f, 0.f, 0.f, 0.f};
  floatx4 acc[4][4];
#pragma unroll
  for (int i = 0; i < 4; ++i)
#pragma unroll
    for (int j = 0; j < 4; ++j) acc[i][j] = zz;

  for (int kt = 0; kt < 768; kt += 32) {
#pragma unroll
    for (int c = 0; c < 2; ++c) {
      int idx = (wid * 2 + c) * 64 + lane;
      int row = idx >> 2, kc = idx & 3;
      gload16(A + (size_t)(m0 + row) * 768 + kt + kc * 8,
              (char*)Alds + (wid * 2 + c) * 1024);
      gload16(Bt + (size_t)(n0 + row) * 768 + kt + kc * 8,
              (char*)Blds + (wid * 2 + c) * 1024);
    }
    __syncthreads();
    bf16x8 af[4], bfr[4];
#pragma unroll
    for (int i = 0; i < 4; ++i) {
      af[i]  = *(const bf16x8*)&Alds[(wr * 64 + i * 16 + l15) * 32 + l4 * 8];
      bfr[i] = *(const bf16x8*)&Blds[(wc * 64 + i * 16 + l15) * 32 + l4 * 8];
    }
#pragma unroll
    for (int i = 0; i < 4; ++i)
#pragma unroll
      for (int j = 0; j < 4; ++j)
        acc[i][j] = __builtin_amdgcn_mfma_f32_16x16x32_bf16(af[i], bfr[j], acc[i][j], 0, 0, 0);
    __syncthreads();
  }

#pragma unroll
  for (int i = 0; i < 4; ++i) {
    int row = m0 + wr * 64 + i * 16 + l4 * 4;
#pragma unroll
    for (int j = 0; j < 4; ++j) {
      int col = n0 + wc * 64 + j * 16 + l15;
      float bv = bias[col];
#pragma unroll
      for (int r = 0; r < 4; ++r) {
        float v = acc[i][j][r] + bv;
        if (OUTF32) ((float*)Cv)[(size_t)(row + r) * ldc + col] = v;
        else        ((u16*)Cv)[(size_t)(row + r) * ldc + col] = f2bf(v);
      }
    }
  }
}

// ---------------- fused attention ----------------
// 1536 blocks (4 q-tiles x 12 heads x 32 batch), 512 thr (8 waves), wave = 16 q-rows.
// LDS 64KB: K dbuf 2x16KB (tiled), V 16KB (tiled, reg-staged early), P 8x2KB.
__global__ __launch_bounds__(512) void attn_kernel(const u16* __restrict__ qkv,
                                                   const float* __restrict__ mask,
                                                   u16* __restrict__ ctx) {
  __shared__ __align__(16) char lds[65536];
  char* sK = lds;            // 2 x [128][64] bf16, byte ^= ((s&7)<<4)
  char* sV = lds + 32768;    // [64][128] bf16 (V^T), byte = d*256 + (4sp ^ ((d&7)<<4) ^ (((d>>3)&3)<<5))
  char* sP = lds + 49152;    // 8 waves x [16][64] bf16, byte ^= ((r&7)<<4)

  // XCD swizzle: natural bid = qt + 4*(h + 12*b); groups of 4 (same b,h) land on one XCD.
  const int bid = blockIdx.x;
  const int wg = (bid & 7) * 192 + (bid >> 3);
  const int qt = wg & 3;
  const int h = (wg >> 2) % 12;
  const int b = wg / 48;

  const int tid = threadIdx.x;
  const int lane = tid & 63, w = tid >> 6;
  const int l15 = lane & 15, l4 = lane >> 4;
  const int hi = lane >> 3, doct = lane & 7;

  const u16* base = qkv + (size_t)b * 512 * 2304 + h * 64;
  const u16* Qg = base;
  const u16* Kg = base + 768;
  const u16* Vg = base + 1536;

  // stage K tile t (rows t*128..t*128+127) into buffer kb; pre-swizzled source.
  auto stageK = [&](int t, int kb) {
    int csw = doct ^ hi;  // row&7 == hi (rows 8-aligned per gload)
    const u16* src = Kg + (size_t)(t * 128 + w * 16) * 2304;
#pragma unroll
    for (int i = 0; i < 2; ++i)
      gload16(src + (size_t)(i * 8 + hi) * 2304 + csw * 8,
              sK + kb * 16384 + (w * 2 + i) * 1024);
  };

  stageK(0, 0);

  // pre-issue ALL V loads (T14): thread owns 2 rows x 8 d per tile.
  const int vp_ = w * 8 + hi;           // s-pair index 0..63 within tile
  uint4 vr0[4], vr1[4];
#pragma unroll
  for (int t = 0; t < 4; ++t) {
    const u16* vp = Vg + (size_t)(t * 128 + vp_ * 2) * 2304 + doct * 8;
    vr0[t] = *(const uint4*)vp;
    vr1[t] = *(const uint4*)(vp + 2304);
  }

  // Q fragments
  const int qrow = qt * 128 + w * 16 + l15;
  const u16* qp = Qg + (size_t)qrow * 2304 + l4 * 8;
  bf16x8 qf0 = *(const bf16x8*)qp;
  bf16x8 qf1 = *(const bf16x8*)(qp + 32);

  floatx4 zz = {0.f, 0.f, 0.f, 0.f};
  floatx4 sacc[32];
#pragma unroll
  for (int ct = 0; ct < 32; ++ct) sacc[ct] = zz;

  __syncthreads();   // K0 staged (drains V/Q loads too, issued once)

  // ---- phase A: QK^T over 4 K-tiles, double-buffered ----
  for (int t = 0; t < 4; ++t) {
    if (t < 3) stageK(t + 1, (t + 1) & 1);
    const char* kbuf = sK + (t & 1) * 16384;
#pragma unroll
    for (int ct = 0; ct < 8; ++ct) {
      int s = ct * 16 + l15;
      const char* kr = kbuf + s * 128;
      int swz = (s & 7) << 4;
      bf16x8 k0 = *(const bf16x8*)(kr + ((l4 * 16) ^ swz));
      bf16x8 k1 = *(const bf16x8*)(kr + ((64 + l4 * 16) ^ swz));
      sacc[t * 8 + ct] = __builtin_amdgcn_mfma_f32_16x16x32_bf16(qf0, k0, sacc[t * 8 + ct], 0, 0, 0);
      sacc[t * 8 + ct] = __builtin_amdgcn_mfma_f32_16x16x32_bf16(qf1, k1, sacc[t * 8 + ct], 0, 0, 0);
    }
    __syncthreads();
  }

  // ---- softmax: full row in regs, reduce over 16-lane group ----
  const float* mrow = mask + (size_t)b * 512;
  float mx[4] = {-1e30f, -1e30f, -1e30f, -1e30f};
#pragma unroll
  for (int ct = 0; ct < 32; ++ct) {
    float mv = mrow[ct * 16 + l15];
#pragma unroll
    for (int j = 0; j < 4; ++j) {
      float v = sacc[ct][j] * 0.125f + mv;
      sacc[ct][j] = v;
      mx[j] = fmaxf(mx[j], v);
    }
  }
#pragma unroll
  for (int xm = 1; xm < 16; xm <<= 1)
#pragma unroll
    for (int j = 0; j < 4; ++j) mx[j] = fmaxf(mx[j], __shfl_xor(mx[j], xm, 64));
  float sum[4] = {0.f, 0.f, 0.f, 0.f};
#pragma unroll
  for (int ct = 0; ct < 32; ++ct)
#pragma unroll
    for (int j = 0; j < 4; ++j) {
      float e = __expf(sacc[ct][j] - mx[j]);
      sacc[ct][j] = e;
      sum[j] += e;
    }
#pragma unroll
  for (int xm = 1; xm < 16; xm <<= 1)
#pragma unroll
    for (int j = 0; j < 4; ++j) sum[j] += __shfl_xor(sum[j], xm, 64);
  float rinv[4];
#pragma unroll
  for (int j = 0; j < 4; ++j) rinv[j] = 1.0f / sum[j];
#pragma unroll
  for (int ct = 0; ct < 32; ++ct)
#pragma unroll
    for (int j = 0; j < 4; ++j) sacc[ct][j] *= rinv[j];

  // ---- phase C: PV over 4 V-tiles (single-buffered V, loads already in regs) ----
  floatx4 oacc[4];
#pragma unroll
  for (int dt = 0; dt < 4; ++dt) oacc[dt] = zz;

  char* pw = sP + w * 2048;
  for (int t = 0; t < 4; ++t) {
    if (t > 0) __syncthreads();   // prior tile's reads done
    // write V tile t (transposed, conflict-free swizzle)
    const u16* pa = (const u16*)&vr0[t];
    const u16* pb = (const u16*)&vr1[t];
#pragma unroll
    for (int j = 0; j < 8; ++j) {
      int d = doct * 8 + j;
      uint32_t val = (uint32_t)pa[j] | ((uint32_t)pb[j] << 16);
      *(uint32_t*)(sV + d * 256 + ((4 * vp_) ^ ((d & 7) << 4) ^ (((d >> 3) & 3) << 5))) = val;
    }
    __syncthreads();

#pragma unroll
    for (int half = 0; half < 2; ++half) {
      // write P chunk [16 rows][64 cols] (cols = s-range half*64 within tile)
#pragma unroll
      for (int cc = 0; cc < 4; ++cc) {
        int ct = t * 8 + half * 4 + cc;
#pragma unroll
        for (int j = 0; j < 4; ++j) {
          int r = l4 * 4 + j;
          *(u16*)(pw + r * 128 + ((2 * (cc * 16 + l15)) ^ ((r & 7) << 4))) = f2bf(sacc[ct][j]);
        }
      }
#pragma unroll
      for (int ks = 0; ks < 2; ++ks) {
        int c0 = ks * 32 + l4 * 8;
        bf16x8 pf = *(const bf16x8*)(pw + l15 * 128 + ((2 * c0) ^ ((l15 & 7) << 4)));
        int spl0 = (half * 2 + ks) * 16 + l4 * 4;   // word index within sV row
#pragma unroll
        for (int dt = 0; dt < 4; ++dt) {
          int dd = dt * 16 + l15;
          bf16x8 vf = *(const bf16x8*)(sV + dd * 256 +
              ((4 * spl0) ^ ((dd & 7) << 4) ^ (((dd >> 3) & 3) << 5)));
          oacc[dt] = __builtin_amdgcn_mfma_f32_16x16x32_bf16(pf, vf, oacc[dt], 0, 0, 0);
        }
      }
    }
  }

  const size_t obase = ((size_t)b * 512 + qt * 128 + w * 16) * 768 + h * 64;
#pragma unroll
  for (int dt = 0; dt < 4; ++dt)
#pragma unroll
    for (int r = 0; r < 4; ++r)
      ctx[obase + (size_t)(l4 * 4 + r) * 768 + dt * 16 + l15] = f2bf(oacc[dt][r]);
}

// ---------------- launch ----------------
extern "C" void kernel_launch(void* const* d_in, const int* in_sizes, int n_in,
                              void* d_out, int out_size, void* d_ws, size_t ws_size,
                              hipStream_t stream) {
  const float* x    = (const float*)d_in[0];
  const float* mask = (const float*)d_in[1];
  const float* Wq   = (const float*)d_in[2];
  const float* bq   = (const float*)d_in[3];
  const float* Wk   = (const float*)d_in[4];
  const float* bk   = (const float*)d_in[5];
  const float* Wv   = (const float*)d_in[6];
  const float* bv   = (const float*)d_in[7];
  const float* Wo   = (const float*)d_in[8];
  const float* bo   = (const float*)d_in[9];
  float* out = (float*)d_out;

  char* ws = (char*)d_ws;
  u16*   xb   = (u16*)ws;                          // 16384*768   bf16
  u16*   ctx  = (u16*)(ws + 25165824);             // 16384*768   bf16
  u16*   qkv  = (u16*)(ws + 50331648);             // 16384*2304  bf16
  u16*   wtq  = (u16*)(ws + 125829120);            // 2304*768    bf16
  u16*   wto  = (u16*)(ws + 129368064);            // 768*768     bf16
  float* bqkv = (float*)(ws + 130547712);          // 2304        f32

  cast_x_kernel<<<6144, 256, 0, stream>>>(x, xb);
  prep_wqkv_kernel<<<6912, 256, 0, stream>>>(Wq, Wk, Wv, bq, bk, bv, wtq, bqkv);
  prep_wo_kernel<<<2304, 256, 0, stream>>>(Wo, wto);
  gemm_bt_kernel<0><<<dim3(128, 18), 256, 0, stream>>>(xb, wtq, bqkv, (void*)qkv, 2304);
  attn_kernel<<<dim3(1536), dim3(512), 0, stream>>>(qkv, mask, ctx);
  gemm_bt_kernel<1><<<dim3(128, 6), 256, 0, stream>>>(ctx, wto, bo, (void*)out, 768);
}